// Round 18
// baseline (571.745 us; speedup 1.0000x reference)
//
#include <hip/hip_runtime.h>
#include <hip/hip_bf16.h>

#define N_NODES 200000
#define N_EDGES 600000
#define N_GRAPHS 4000
#define EMB 128
#define LAYERS 5
#define BN_EPS 1e-5f

#define SCAN_CHUNK 2048                   // 256 threads x 8
#define N_CHUNKS ((N_NODES + SCAN_CHUNK - 1) / SCAN_CHUNK)   // 98

typedef __attribute__((ext_vector_type(8))) short short8;            // 8 bf16 (4 VGPRs)
typedef __attribute__((ext_vector_type(8))) unsigned short ushort8v; // bf16 row chunk
typedef __attribute__((ext_vector_type(4))) float float4v;           // MFMA C/D

// split f32 -> bf16 hi (truncate) + bf16 lo (truncate of residual)
__device__ __forceinline__ void bf16split(float f, unsigned short& hi, unsigned short& lo) {
    unsigned u = __float_as_uint(f);
    hi = (unsigned short)(u >> 16);
    float hf = __uint_as_float((unsigned)hi << 16);
    lo = (unsigned short)(__float_as_uint(f - hf) >> 16);
}

// f32 -> bf16 round-to-nearest-even (XL / combo / aemb storage)
__device__ __forceinline__ unsigned short f2bf_rne(float f) {
    unsigned u = __float_as_uint(f);
    u += 0x7FFF + ((u >> 16) & 1);
    return (unsigned short)(u >> 16);
}
__device__ __forceinline__ float bf2f(unsigned short h) {
    return __uint_as_float((unsigned)h << 16);
}

// ---------------------------------------------------------------------------
// Fused prep kernel: 6 independent jobs partitioned by blockIdx.
// ---------------------------------------------------------------------------
#define CNT_BLOCKS 2344
#define WP_BASE   CNT_BLOCKS
#define WP_BLOCKS 320
#define CB_BASE   (WP_BASE + WP_BLOCKS)
#define CB_BLOCKS 1280
#define BN_BASE   (CB_BASE + CB_BLOCKS)
#define BN_BLOCKS 3
#define GB_BASE   (BN_BASE + BN_BLOCKS)
#define GB_BLOCKS 16
#define AB_BASE   (GB_BASE + GB_BLOCKS)
#define AB_BLOCKS 288                     // 9*64*128 / 256
#define PREP_BLOCKS (AB_BASE + AB_BLOCKS)

__global__ __launch_bounds__(256) void prep_all(
    const int* __restrict__ ei_src, const int* __restrict__ ei_dst,
    int* __restrict__ dsrc, int* __restrict__ ddst,
    const float* __restrict__ W, unsigned short* __restrict__ whi,
    unsigned short* __restrict__ wlo,
    const float* __restrict__ bemb, unsigned short* __restrict__ combo,
    const float* __restrict__ mean, const float* __restrict__ var,
    const float* __restrict__ gamma, const float* __restrict__ beta,
    float* __restrict__ S, float* __restrict__ T,
    const int* __restrict__ batch, int* __restrict__ gptr,
    const float* __restrict__ aemb, unsigned short* __restrict__ aembb) {
    const int b = blockIdx.x, tid = threadIdx.x;
    if (b < CNT_BLOCKS) {
        const int e = b * 256 + tid;
        if (e < N_EDGES) {
            atomicAdd(&dsrc[ei_src[e]], 1);
            atomicAdd(&ddst[ei_dst[e]], 1);
        }
    } else if (b < CB_BASE) {
        const int idx = (b - WP_BASE) * 256 + tid;      // < 81920, exact
        const int l = idx >> 14, rem = idx & 16383;
        const int k = rem >> 7, n = rem & 127;
        unsigned short hi, lo;
        bf16split(W[idx], hi, lo);
        const int off = (l << 14) + ((((k >> 5) * 8 + (n >> 4)) * 64
                        + ((k >> 3) & 3) * 16 + (n & 15)) << 3) + (k & 7);
        whi[off] = hi;
        wlo[off] = lo;
    } else if (b < BN_BASE) {
        const int idx = (b - CB_BASE) * 256 + tid;      // < 327680, exact
        const int l = idx >> 16;
        const int c = (idx >> 7) & 511;
        const int ch = idx & 127;
        const int a0 = c & 7, a1 = (c >> 3) & 7, a2 = c >> 6;
        combo[(size_t)(l * 512 + c) * EMB + ch] = f2bf_rne(
            bemb[(size_t)((l * 3 + 0) * 8 + a0) * EMB + ch] +
            bemb[(size_t)((l * 3 + 1) * 8 + a1) * EMB + ch] +
            bemb[(size_t)((l * 3 + 2) * 8 + a2) * EMB + ch]);
    } else if (b < GB_BASE) {
        const int i = (b - BN_BASE) * 256 + tid;
        if (i < LAYERS * EMB) {
            float s = gamma[i] / sqrtf(var[i] + BN_EPS);
            S[i] = s;
            T[i] = beta[i] - mean[i] * s;
        }
    } else if (b < AB_BASE) {
        const int g = (b - GB_BASE) * 256 + tid;
        if (g > N_GRAPHS) return;
        if (g == N_GRAPHS) { gptr[g] = N_NODES; return; }
        int lo = 0, hi = N_NODES;
        while (lo < hi) {
            int mid = (lo + hi) >> 1;
            if (batch[mid] < g) lo = mid + 1; else hi = mid;
        }
        gptr[g] = lo;
    } else {
        const int idx = (b - AB_BASE) * 256 + tid;      // < 73728, exact
        aembb[idx] = f2bf_rne(aemb[idx]);
    }
}

// ---------------------------------------------------------------------------
// scan1: per-chunk sums of ddst
// ---------------------------------------------------------------------------
__global__ __launch_bounds__(256) void scan1(const int* __restrict__ deg, int* __restrict__ partial) {
    __shared__ int sd[256];
    const int base = blockIdx.x * SCAN_CHUNK + threadIdx.x * 8;
    int s = 0;
#pragma unroll
    for (int i = 0; i < 8; ++i) { int idx = base + i; s += (idx < N_NODES) ? deg[idx] : 0; }
    sd[threadIdx.x] = s; __syncthreads();
    for (int off = 128; off > 0; off >>= 1) {
        if (threadIdx.x < off) sd[threadIdx.x] += sd[threadIdx.x + off];
        __syncthreads();
    }
    if (threadIdx.x == 0) partial[blockIdx.x] = sd[0];
}

// ---------------------------------------------------------------------------
// scan3: block computes its own offset from partials, then scans its chunk.
// ---------------------------------------------------------------------------
__global__ __launch_bounds__(256) void scan3(const int* __restrict__ deg,
                                             const int* __restrict__ partial,
                                             int* __restrict__ rowptr) {
    __shared__ int sd[256];
    __shared__ int base_off;
    const int tid = threadIdx.x;
    if (tid == 0) {
        int acc = 0;
        for (int i = 0; i < (int)blockIdx.x; ++i) acc += partial[i];
        base_off = acc;
    }
    const int base = blockIdx.x * SCAN_CHUNK + tid * 8;
    int loc[8]; int s = 0;
#pragma unroll
    for (int i = 0; i < 8; ++i) { int idx = base + i; loc[i] = (idx < N_NODES) ? deg[idx] : 0; s += loc[i]; }
    sd[tid] = s; __syncthreads();
    for (int off = 1; off < 256; off <<= 1) {
        int v = (tid >= off) ? sd[tid - off] : 0;
        __syncthreads();
        sd[tid] += v;
        __syncthreads();
    }
    int excl = base_off + sd[tid] - s;
#pragma unroll
    for (int i = 0; i < 8; ++i) {
        int idx = base + i;
        if (idx < N_NODES) { rowptr[idx] = excl; excl += loc[i]; }
    }
    if (blockIdx.x == 0 && tid == 0) rowptr[N_NODES] = N_EDGES;
}

// ---------------------------------------------------------------------------
// Scatter edges into dst-CSR. Packed record: erec = {src|combo<<18, norm}.
// ---------------------------------------------------------------------------
__global__ void scatter_k(const int* __restrict__ srcs, const int* __restrict__ dsts,
                          const int* __restrict__ eattr, const int* __restrict__ dsrc,
                          const int* __restrict__ rowptr, int* __restrict__ fill,
                          int2* __restrict__ erec) {
    int e = blockIdx.x * blockDim.x + threadIdx.x;
    if (e >= N_EDGES) return;
    const int s = srcs[e];
    const int d = dsts[e];
    const int pos = rowptr[d] + atomicAdd(&fill[d], 1);
    const int c = eattr[e * 3] | (eattr[e * 3 + 1] << 3) | (eattr[e * 3 + 2] << 6);
    const float nrm = rsqrtf((float)(dsrc[s] + 1) * (float)(dsrc[d] + 1));
    erec[pos] = make_int2(s | (c << 18), __float_as_int(nrm));
}

// ---------------------------------------------------------------------------
// MFMA phase for 1024-thread / 64-row blocks (enc_gemm).
// ---------------------------------------------------------------------------
__device__ __forceinline__ void mfma_tile64(
    unsigned short (*AhAl)[64][136],
    const short8* __restrict__ Bh, const short8* __restrict__ Bl,
    const float* __restrict__ bias, unsigned short* __restrict__ XLout,
    size_t rows, int tid) {
    const int wave = tid >> 6;          // 0..15
    const int lane = tid & 63;
    const int quad = lane >> 4;
    const int n15  = lane & 15;
    const int rt   = wave & 3;          // row-tile 0..3
    const int cp   = wave >> 2;         // col-pair 0..3
    const int arow = rt * 16 + n15;

    float4v acc0 = (float4v)(0.f);
    float4v acc1 = (float4v)(0.f);
#pragma unroll
    for (int ks = 0; ks < 4; ++ks) {
        const int k0 = ks * 32 + quad * 8;
        const short8 ah = *(const short8*)&AhAl[0][arow][k0];
        const short8 al = *(const short8*)&AhAl[1][arow][k0];
        const short8 bh0 = Bh[(ks * 8 + cp * 2 + 0) * 64 + lane];
        const short8 bl0 = Bl[(ks * 8 + cp * 2 + 0) * 64 + lane];
        const short8 bh1 = Bh[(ks * 8 + cp * 2 + 1) * 64 + lane];
        const short8 bl1 = Bl[(ks * 8 + cp * 2 + 1) * 64 + lane];
        acc0 = __builtin_amdgcn_mfma_f32_16x16x32_bf16(ah, bh0, acc0, 0, 0, 0);
        acc0 = __builtin_amdgcn_mfma_f32_16x16x32_bf16(ah, bl0, acc0, 0, 0, 0);
        acc0 = __builtin_amdgcn_mfma_f32_16x16x32_bf16(al, bh0, acc0, 0, 0, 0);
        acc1 = __builtin_amdgcn_mfma_f32_16x16x32_bf16(ah, bh1, acc1, 0, 0, 0);
        acc1 = __builtin_amdgcn_mfma_f32_16x16x32_bf16(ah, bl1, acc1, 0, 0, 0);
        acc1 = __builtin_amdgcn_mfma_f32_16x16x32_bf16(al, bh1, acc1, 0, 0, 0);
    }

    const size_t rowBase = rows + rt * 16 + quad * 4;
    const int col0 = (cp * 2 + 0) * 16 + n15;
    const int col1 = (cp * 2 + 1) * 16 + n15;
    const float bc0 = bias[col0];
    const float bc1 = bias[col1];
#pragma unroll
    for (int r = 0; r < 4; ++r) {
        XLout[(rowBase + r) * EMB + col0] = f2bf_rne(acc0[r] + bc0);
        XLout[(rowBase + r) * EMB + col1] = f2bf_rne(acc1[r] + bc1);
    }
}

// ---------------------------------------------------------------------------
// MFMA phase for 128-thread / 16-row blocks (gather_gemm): 2 waves, each
// wave 4 C-tiles (cols wave*64..+64) over K=128.
// ---------------------------------------------------------------------------
__device__ __forceinline__ void mfma_tile16w2(
    unsigned short (*AhAl)[16][136],
    const short8* __restrict__ Bh, const short8* __restrict__ Bl,
    const float* __restrict__ bias, unsigned short* __restrict__ XLout,
    size_t rows, int tid) {
    const int wave = tid >> 6;          // 0..1
    const int lane = tid & 63;
    const int quad = lane >> 4;
    const int n15  = lane & 15;
    const int arow = n15;

    float4v acc[4];
#pragma unroll
    for (int j = 0; j < 4; ++j) acc[j] = (float4v)(0.f);

#pragma unroll
    for (int ks = 0; ks < 4; ++ks) {
        const int k0 = ks * 32 + quad * 8;
        const short8 ah = *(const short8*)&AhAl[0][arow][k0];
        const short8 al = *(const short8*)&AhAl[1][arow][k0];
#pragma unroll
        for (int j = 0; j < 4; ++j) {
            const int ct = wave * 4 + j;
            const short8 bh = Bh[(ks * 8 + ct) * 64 + lane];
            const short8 bl = Bl[(ks * 8 + ct) * 64 + lane];
            acc[j] = __builtin_amdgcn_mfma_f32_16x16x32_bf16(ah, bh, acc[j], 0, 0, 0);
            acc[j] = __builtin_amdgcn_mfma_f32_16x16x32_bf16(ah, bl, acc[j], 0, 0, 0);
            acc[j] = __builtin_amdgcn_mfma_f32_16x16x32_bf16(al, bh, acc[j], 0, 0, 0);
        }
    }

    const size_t rowBase = rows + quad * 4;
#pragma unroll
    for (int j = 0; j < 4; ++j) {
        const int col = (wave * 4 + j) * 16 + n15;
        const float bc = bias[col];
#pragma unroll
        for (int r = 0; r < 4; ++r)
            XLout[(rowBase + r) * EMB + col] = f2bf_rne(acc[j][r] + bc);
    }
}

// ---------------------------------------------------------------------------
// Fused atom-encoder + GEMM layer 0 (1024 threads, 64 rows), bf16 aemb.
// ---------------------------------------------------------------------------
__global__ __launch_bounds__(1024, 8) void enc_gemm(
    const int* __restrict__ x, const unsigned short* __restrict__ aembb,
    const unsigned short* __restrict__ whi, const unsigned short* __restrict__ wlo,
    const float* __restrict__ bias, unsigned short* __restrict__ XL) {
    __shared__ unsigned short AhAl[2][64][136];
    const int tid = threadIdx.x;
    const int q = tid & 15, qw = tid >> 4;     // 64 quarter-waves
    const int c0 = q * 8;
    const size_t rows = (size_t)blockIdx.x * 64;

    {
        const size_t n = rows + qw;
        float4 a0 = make_float4(0.f, 0.f, 0.f, 0.f), a1 = a0;
#pragma unroll
        for (int ff = 0; ff < 9; ++ff) {
            const int v = x[n * 9 + ff];
            const ushort8v e = *(const ushort8v*)&aembb[(size_t)(ff * 64 + v) * EMB + c0];
            a0.x += bf2f(e[0]); a0.y += bf2f(e[1]);
            a0.z += bf2f(e[2]); a0.w += bf2f(e[3]);
            a1.x += bf2f(e[4]); a1.y += bf2f(e[5]);
            a1.z += bf2f(e[6]); a1.w += bf2f(e[7]);
        }
        ushort4 hi, lo;
        bf16split(a0.x, hi.x, lo.x); bf16split(a0.y, hi.y, lo.y);
        bf16split(a0.z, hi.z, lo.z); bf16split(a0.w, hi.w, lo.w);
        *(ushort4*)&AhAl[0][qw][c0] = hi;
        *(ushort4*)&AhAl[1][qw][c0] = lo;
        bf16split(a1.x, hi.x, lo.x); bf16split(a1.y, hi.y, lo.y);
        bf16split(a1.z, hi.z, lo.z); bf16split(a1.w, hi.w, lo.w);
        *(ushort4*)&AhAl[0][qw][c0 + 4] = hi;
        *(ushort4*)&AhAl[1][qw][c0 + 4] = lo;
    }
    __syncthreads();
    mfma_tile64(AhAl, (const short8*)whi, (const short8*)wlo, bias, XL, rows, tid);
}

// ---------------------------------------------------------------------------
// Fused gather(layer l) + BN_l + ReLU + GEMM(layer l+1) (128 threads,
// 16 rows): 16 EIGHTH-waves x 1 node, 16 channels/lane. Per edge per lane:
// 1 int2 record + 2 xv + 2 cb loads = 2.5 VMEM issues per 8 channels
// (was 4). 2x chains per row-set, 16 barrier groups/CU.
// ---------------------------------------------------------------------------
__global__ __launch_bounds__(128, 8) void gather_gemm(
    const int* __restrict__ rowptr, const int2* __restrict__ erec,
    const unsigned short* __restrict__ combo,
    const float* __restrict__ root, const int* __restrict__ dsrc,
    const float* __restrict__ bnS, const float* __restrict__ bnT,
    const unsigned short* __restrict__ whi, const unsigned short* __restrict__ wlo,
    const float* __restrict__ bias,
    const unsigned short* __restrict__ XLin, unsigned short* __restrict__ XLout) {
    __shared__ unsigned short AhAl[2][16][136];
    const int tid = threadIdx.x;
    const int o = tid & 7, qw = tid >> 3;      // 16 eighth-waves
    const int c0 = o * 16;
    const size_t rows = (size_t)blockIdx.x * 16;

    {
        const size_t n = rows + qw;
        const float dinv = 1.0f / (float)(dsrc[n] + 1);
        float4 a0, a1, a2, a3;
        {
            const ushort8v xn0 = *(const ushort8v*)&XLin[n * EMB + c0];
            const ushort8v xn1 = *(const ushort8v*)&XLin[n * EMB + c0 + 8];
            const float4 r0 = *(const float4*)&root[c0];
            const float4 r1 = *(const float4*)&root[c0 + 4];
            const float4 r2 = *(const float4*)&root[c0 + 8];
            const float4 r3 = *(const float4*)&root[c0 + 12];
            a0.x = fmaxf(bf2f(xn0[0]) + r0.x, 0.f) * dinv;
            a0.y = fmaxf(bf2f(xn0[1]) + r0.y, 0.f) * dinv;
            a0.z = fmaxf(bf2f(xn0[2]) + r0.z, 0.f) * dinv;
            a0.w = fmaxf(bf2f(xn0[3]) + r0.w, 0.f) * dinv;
            a1.x = fmaxf(bf2f(xn0[4]) + r1.x, 0.f) * dinv;
            a1.y = fmaxf(bf2f(xn0[5]) + r1.y, 0.f) * dinv;
            a1.z = fmaxf(bf2f(xn0[6]) + r1.z, 0.f) * dinv;
            a1.w = fmaxf(bf2f(xn0[7]) + r1.w, 0.f) * dinv;
            a2.x = fmaxf(bf2f(xn1[0]) + r2.x, 0.f) * dinv;
            a2.y = fmaxf(bf2f(xn1[1]) + r2.y, 0.f) * dinv;
            a2.z = fmaxf(bf2f(xn1[2]) + r2.z, 0.f) * dinv;
            a2.w = fmaxf(bf2f(xn1[3]) + r2.w, 0.f) * dinv;
            a3.x = fmaxf(bf2f(xn1[4]) + r3.x, 0.f) * dinv;
            a3.y = fmaxf(bf2f(xn1[5]) + r3.y, 0.f) * dinv;
            a3.z = fmaxf(bf2f(xn1[6]) + r3.z, 0.f) * dinv;
            a3.w = fmaxf(bf2f(xn1[7]) + r3.w, 0.f) * dinv;
        }

        const int beg = rowptr[n], end = rowptr[n + 1];
        int2 rec = make_int2(0, 0);
        if (beg < end) rec = erec[beg];
        for (int e = beg; e < end; ++e) {
            const int pk = rec.x;
            const float w = __int_as_float(rec.y);
            if (e + 1 < end) rec = erec[e + 1];           // prefetch
            const size_t sb = (size_t)(pk & 0x3FFFF) * EMB + c0;
            const size_t cbx = (size_t)(pk >> 18) * EMB + c0;
            const ushort8v xv0 = *(const ushort8v*)&XLin[sb];
            const ushort8v xv1 = *(const ushort8v*)&XLin[sb + 8];
            const ushort8v cb0 = *(const ushort8v*)&combo[cbx];
            const ushort8v cb1 = *(const ushort8v*)&combo[cbx + 8];
            a0.x += fmaxf(bf2f(xv0[0]) + bf2f(cb0[0]), 0.f) * w;
            a0.y += fmaxf(bf2f(xv0[1]) + bf2f(cb0[1]), 0.f) * w;
            a0.z += fmaxf(bf2f(xv0[2]) + bf2f(cb0[2]), 0.f) * w;
            a0.w += fmaxf(bf2f(xv0[3]) + bf2f(cb0[3]), 0.f) * w;
            a1.x += fmaxf(bf2f(xv0[4]) + bf2f(cb0[4]), 0.f) * w;
            a1.y += fmaxf(bf2f(xv0[5]) + bf2f(cb0[5]), 0.f) * w;
            a1.z += fmaxf(bf2f(xv0[6]) + bf2f(cb0[6]), 0.f) * w;
            a1.w += fmaxf(bf2f(xv0[7]) + bf2f(cb0[7]), 0.f) * w;
            a2.x += fmaxf(bf2f(xv1[0]) + bf2f(cb1[0]), 0.f) * w;
            a2.y += fmaxf(bf2f(xv1[1]) + bf2f(cb1[1]), 0.f) * w;
            a2.z += fmaxf(bf2f(xv1[2]) + bf2f(cb1[2]), 0.f) * w;
            a2.w += fmaxf(bf2f(xv1[3]) + bf2f(cb1[3]), 0.f) * w;
            a3.x += fmaxf(bf2f(xv1[4]) + bf2f(cb1[4]), 0.f) * w;
            a3.y += fmaxf(bf2f(xv1[5]) + bf2f(cb1[5]), 0.f) * w;
            a3.z += fmaxf(bf2f(xv1[6]) + bf2f(cb1[6]), 0.f) * w;
            a3.w += fmaxf(bf2f(xv1[7]) + bf2f(cb1[7]), 0.f) * w;
        }

        const float4 s0 = *(const float4*)&bnS[c0];
        const float4 s1 = *(const float4*)&bnS[c0 + 4];
        const float4 s2 = *(const float4*)&bnS[c0 + 8];
        const float4 s3 = *(const float4*)&bnS[c0 + 12];
        const float4 t0 = *(const float4*)&bnT[c0];
        const float4 t1 = *(const float4*)&bnT[c0 + 4];
        const float4 t2 = *(const float4*)&bnT[c0 + 8];
        const float4 t3 = *(const float4*)&bnT[c0 + 12];
        float h[16];
        h[0]  = fmaxf(fmaf(a0.x, s0.x, t0.x), 0.f);
        h[1]  = fmaxf(fmaf(a0.y, s0.y, t0.y), 0.f);
        h[2]  = fmaxf(fmaf(a0.z, s0.z, t0.z), 0.f);
        h[3]  = fmaxf(fmaf(a0.w, s0.w, t0.w), 0.f);
        h[4]  = fmaxf(fmaf(a1.x, s1.x, t1.x), 0.f);
        h[5]  = fmaxf(fmaf(a1.y, s1.y, t1.y), 0.f);
        h[6]  = fmaxf(fmaf(a1.z, s1.z, t1.z), 0.f);
        h[7]  = fmaxf(fmaf(a1.w, s1.w, t1.w), 0.f);
        h[8]  = fmaxf(fmaf(a2.x, s2.x, t2.x), 0.f);
        h[9]  = fmaxf(fmaf(a2.y, s2.y, t2.y), 0.f);
        h[10] = fmaxf(fmaf(a2.z, s2.z, t2.z), 0.f);
        h[11] = fmaxf(fmaf(a2.w, s2.w, t2.w), 0.f);
        h[12] = fmaxf(fmaf(a3.x, s3.x, t3.x), 0.f);
        h[13] = fmaxf(fmaf(a3.y, s3.y, t3.y), 0.f);
        h[14] = fmaxf(fmaf(a3.z, s3.z, t3.z), 0.f);
        h[15] = fmaxf(fmaf(a3.w, s3.w, t3.w), 0.f);
        ushort4 hi, lo;
#pragma unroll
        for (int g4 = 0; g4 < 4; ++g4) {
            bf16split(h[g4 * 4 + 0], hi.x, lo.x);
            bf16split(h[g4 * 4 + 1], hi.y, lo.y);
            bf16split(h[g4 * 4 + 2], hi.z, lo.z);
            bf16split(h[g4 * 4 + 3], hi.w, lo.w);
            *(ushort4*)&AhAl[0][qw][c0 + g4 * 4] = hi;
            *(ushort4*)&AhAl[1][qw][c0 + g4 * 4] = lo;
        }
    }
    __syncthreads();
    mfma_tile16w2(AhAl, (const short8*)whi, (const short8*)wlo, bias, XLout, rows, tid);
}

// ---------------------------------------------------------------------------
// Fused final gather(layer 4) + BN4 + pool + head. Flat edge-range pooling
// (BN affine + pool linear), one 512-thread block per graph, no atomics.
// ---------------------------------------------------------------------------
__global__ __launch_bounds__(512) void gather_pool_head(
    const int* __restrict__ rowptr, const int2* __restrict__ erec,
    const unsigned short* __restrict__ combo,
    const float* __restrict__ root, const int* __restrict__ dsrc,
    const float* __restrict__ S4, const float* __restrict__ T4,
    const int* __restrict__ gptr, const unsigned short* __restrict__ XLin,
    const float* __restrict__ HW, const float* __restrict__ hb,
    float* __restrict__ OUT) {
    __shared__ float red[32][EMB];
    __shared__ float hr[EMB];
    const int gph = blockIdx.x;
    const int q = threadIdx.x & 15, qw = threadIdx.x >> 4;   // 32 quarter-waves
    const int c0 = q * 8;
    const int nbeg = gptr[gph], nend = gptr[gph + 1];
    const int ebeg = rowptr[nbeg], eend = rowptr[nend];

    const float4 r40 = *(const float4*)&root[c0];
    const float4 r41 = *(const float4*)&root[c0 + 4];

    float4 seg0 = make_float4(0.f, 0.f, 0.f, 0.f), seg1 = seg0;
    // self terms over the graph's node range
    for (int n = nbeg + qw; n < nend; n += 32) {
        const float dinv = 1.0f / (float)(dsrc[n] + 1);
        const ushort8v xn = *(const ushort8v*)&XLin[(size_t)n * EMB + c0];
        seg0.x += fmaxf(bf2f(xn[0]) + r40.x, 0.f) * dinv;
        seg0.y += fmaxf(bf2f(xn[1]) + r40.y, 0.f) * dinv;
        seg0.z += fmaxf(bf2f(xn[2]) + r40.z, 0.f) * dinv;
        seg0.w += fmaxf(bf2f(xn[3]) + r40.w, 0.f) * dinv;
        seg1.x += fmaxf(bf2f(xn[4]) + r41.x, 0.f) * dinv;
        seg1.y += fmaxf(bf2f(xn[5]) + r41.y, 0.f) * dinv;
        seg1.z += fmaxf(bf2f(xn[6]) + r41.z, 0.f) * dinv;
        seg1.w += fmaxf(bf2f(xn[7]) + r41.w, 0.f) * dinv;
    }
    // messages over the graph's contiguous edge range (dst identity unused)
    for (int i = ebeg + qw; i < eend; i += 32) {
        const int2 rec = erec[i];
        const int pk = rec.x;
        const float w = __int_as_float(rec.y);
        const size_t sb = (size_t)(pk & 0x3FFFF) * EMB + c0;
        const size_t cbx = (size_t)(pk >> 18) * EMB + c0;
        const ushort8v xv = *(const ushort8v*)&XLin[sb];
        const ushort8v cb = *(const ushort8v*)&combo[cbx];
        seg0.x += fmaxf(bf2f(xv[0]) + bf2f(cb[0]), 0.f) * w;
        seg0.y += fmaxf(bf2f(xv[1]) + bf2f(cb[1]), 0.f) * w;
        seg0.z += fmaxf(bf2f(xv[2]) + bf2f(cb[2]), 0.f) * w;
        seg0.w += fmaxf(bf2f(xv[3]) + bf2f(cb[3]), 0.f) * w;
        seg1.x += fmaxf(bf2f(xv[4]) + bf2f(cb[4]), 0.f) * w;
        seg1.y += fmaxf(bf2f(xv[5]) + bf2f(cb[5]), 0.f) * w;
        seg1.z += fmaxf(bf2f(xv[6]) + bf2f(cb[6]), 0.f) * w;
        seg1.w += fmaxf(bf2f(xv[7]) + bf2f(cb[7]), 0.f) * w;
    }
    *(float4*)&red[qw][c0] = seg0;
    *(float4*)&red[qw][c0 + 4] = seg1;
    __syncthreads();

    const int t = threadIdx.x;
    if (t < EMB) {
        float v = 0.f;
#pragma unroll
        for (int r = 0; r < 32; ++r) v += red[r][t];
        hr[t] = fmaf(v, S4[t], T4[t] * (float)(nend - nbeg));
    }
    __syncthreads();
    if (t < EMB) {
        float o = hb[t];
#pragma unroll 8
        for (int k = 0; k < EMB; ++k) o = fmaf(hr[k], HW[(size_t)k * EMB + t], o);
        OUT[(size_t)gph * EMB + t] = o;
    }
}

extern "C" void kernel_launch(void* const* d_in, const int* in_sizes, int n_in,
                              void* d_out, int out_size, void* d_ws, size_t ws_size,
                              hipStream_t stream) {
    const int*   x     = (const int*)d_in[0];
    const int*   ei    = (const int*)d_in[1];    // [2, E]: src then dst
    const int*   ea    = (const int*)d_in[2];    // [E, 3]
    const int*   batch = (const int*)d_in[3];
    const float* aemb  = (const float*)d_in[4];
    const float* bemb  = (const float*)d_in[5];
    const float* W     = (const float*)d_in[6];
    const float* b     = (const float*)d_in[7];
    const float* root  = (const float*)d_in[8];
    const float* bnm   = (const float*)d_in[9];
    const float* bnv   = (const float*)d_in[10];
    const float* bng   = (const float*)d_in[11];
    const float* bnb   = (const float*)d_in[12];
    const float* hW    = (const float*)d_in[13];
    const float* hb    = (const float*)d_in[14];
    float* out = (float*)d_out;

    const size_t NF = (size_t)N_NODES * EMB;
    // bufA/bufB bf16; combo bf16; aembb bf16; erec int2
    const size_t n_float = NF + (size_t)LAYERS * 512 * EMB / 2
                         + 2 * LAYERS * EMB
                         + 2 * ((size_t)LAYERS * 16384 / 2 + 64)
                         + (9 * 64 * EMB / 2 + 64);
    const size_t n_int   = 2 * (size_t)N_EDGES           // erec
                         + 3 * (size_t)N_NODES + (N_NODES + 4) + 128
                         + (N_GRAPHS + 4);
    const size_t need = (n_float + n_int) * sizeof(float);
    if (ws_size < need) return;  // defensive: fail cleanly, don't fault

    float* f     = (float*)d_ws;
    unsigned short* bufA = (unsigned short*)f; f += NF / 2;
    unsigned short* bufB = (unsigned short*)f; f += NF / 2;
    unsigned short* combo = (unsigned short*)f; f += (size_t)LAYERS * 512 * EMB / 2;
    float* S     = f;                          f += LAYERS * EMB;
    float* T     = f;                          f += LAYERS * EMB;
    unsigned short* whi = (unsigned short*)f;  f += (size_t)LAYERS * 16384 / 2 + 64;
    unsigned short* wlo = (unsigned short*)f;  f += (size_t)LAYERS * 16384 / 2 + 64;
    unsigned short* aembb = (unsigned short*)f; f += 9 * 64 * EMB / 2 + 64;
    // all float-slot counts above are even -> 8B alignment holds here
    int2*  erec  = (int2*)f;
    int*   ip    = (int*)(erec + N_EDGES);
    int*   dsrc    = ip;                       ip += N_NODES;
    int*   ddst    = ip;                       ip += N_NODES;
    int*   fill    = ip;                       ip += N_NODES;
    int*   rowptr  = ip;                       ip += N_NODES + 4;
    int*   partial = ip;                       ip += 128;
    int*   gptr    = ip;                       ip += N_GRAPHS + 4;

    hipMemsetAsync(dsrc, 0, 3 * (size_t)N_NODES * sizeof(int), stream);

    prep_all<<<PREP_BLOCKS, 256, 0, stream>>>(
        ei, ei + N_EDGES, dsrc, ddst, W, whi, wlo, bemb, combo,
        bnm, bnv, bng, bnb, S, T, batch, gptr, aemb, aembb);
    scan1<<<N_CHUNKS, 256, 0, stream>>>(ddst, partial);
    scan3<<<N_CHUNKS, 256, 0, stream>>>(ddst, partial, rowptr);
    scatter_k<<<(N_EDGES + 255) / 256, 256, 0, stream>>>(ei, ei + N_EDGES, ea, dsrc,
                                                         rowptr, fill, erec);

    // L0: encoder fused with GEMM-0 -> XL0 (bf16) in bufA (64-row blocks)
    enc_gemm<<<N_NODES / 64, 1024, 0, stream>>>(x, aembb, whi, wlo, b, bufA);

    // L0..L3 gathers fused with next layer's GEMM (128-thread / 16-row).
    unsigned short* in    = bufA;
    unsigned short* other = bufB;
    for (int l = 0; l < 4; ++l) {
        gather_gemm<<<N_NODES / 16, 128, 0, stream>>>(
            rowptr, erec, combo + (size_t)l * 512 * EMB, root + l * EMB, dsrc,
            S + l * EMB, T + l * EMB,
            whi + (size_t)(l + 1) * 16384, wlo + (size_t)(l + 1) * 16384,
            b + (l + 1) * EMB, /*XLin=*/in, /*XLout=*/other);
        unsigned short* t0 = in; in = other; other = t0;
    }

    // L4 gather fused with BN4 + pool + head, one block per graph, no atomics
    gather_pool_head<<<N_GRAPHS, 512, 0, stream>>>(
        rowptr, erec, combo + (size_t)4 * 512 * EMB, root + 4 * EMB, dsrc,
        S + 4 * EMB, T + 4 * EMB, gptr, /*XLin=*/in, hW, hb, out);
}

// Round 19
// 543.444 us; speedup vs baseline: 1.0521x; 1.0521x over previous
//
#include <hip/hip_runtime.h>
#include <hip/hip_bf16.h>

#define N_NODES 200000
#define N_EDGES 600000
#define N_GRAPHS 4000
#define EMB 128
#define LAYERS 5
#define BN_EPS 1e-5f

#define SCAN_CHUNK 2048                   // 256 threads x 8
#define N_CHUNKS ((N_NODES + SCAN_CHUNK - 1) / SCAN_CHUNK)   // 98

typedef __attribute__((ext_vector_type(8))) short short8;            // 8 bf16 (4 VGPRs)
typedef __attribute__((ext_vector_type(8))) unsigned short ushort8v; // bf16 row chunk
typedef __attribute__((ext_vector_type(4))) float float4v;           // MFMA C/D

// split f32 -> bf16 hi (truncate) + bf16 lo (truncate of residual)
__device__ __forceinline__ void bf16split(float f, unsigned short& hi, unsigned short& lo) {
    unsigned u = __float_as_uint(f);
    hi = (unsigned short)(u >> 16);
    float hf = __uint_as_float((unsigned)hi << 16);
    lo = (unsigned short)(__float_as_uint(f - hf) >> 16);
}

// f32 -> bf16 round-to-nearest-even (XL / combo / aemb storage)
__device__ __forceinline__ unsigned short f2bf_rne(float f) {
    unsigned u = __float_as_uint(f);
    u += 0x7FFF + ((u >> 16) & 1);
    return (unsigned short)(u >> 16);
}
__device__ __forceinline__ float bf2f(unsigned short h) {
    return __uint_as_float((unsigned)h << 16);
}

// ---------------------------------------------------------------------------
// Fused prep kernel: 6 independent jobs partitioned by blockIdx.
// ---------------------------------------------------------------------------
#define CNT_BLOCKS 2344
#define WP_BASE   CNT_BLOCKS
#define WP_BLOCKS 320
#define CB_BASE   (WP_BASE + WP_BLOCKS)
#define CB_BLOCKS 1280
#define BN_BASE   (CB_BASE + CB_BLOCKS)
#define BN_BLOCKS 3
#define GB_BASE   (BN_BASE + BN_BLOCKS)
#define GB_BLOCKS 16
#define AB_BASE   (GB_BASE + GB_BLOCKS)
#define AB_BLOCKS 288                     // 9*64*128 / 256
#define PREP_BLOCKS (AB_BASE + AB_BLOCKS)

__global__ __launch_bounds__(256) void prep_all(
    const int* __restrict__ ei_src, const int* __restrict__ ei_dst,
    int* __restrict__ dsrc, int* __restrict__ ddst,
    const float* __restrict__ W, unsigned short* __restrict__ whi,
    unsigned short* __restrict__ wlo,
    const float* __restrict__ bemb, unsigned short* __restrict__ combo,
    const float* __restrict__ mean, const float* __restrict__ var,
    const float* __restrict__ gamma, const float* __restrict__ beta,
    float* __restrict__ S, float* __restrict__ T,
    const int* __restrict__ batch, int* __restrict__ gptr,
    const float* __restrict__ aemb, unsigned short* __restrict__ aembb) {
    const int b = blockIdx.x, tid = threadIdx.x;
    if (b < CNT_BLOCKS) {
        const int e = b * 256 + tid;
        if (e < N_EDGES) {
            atomicAdd(&dsrc[ei_src[e]], 1);
            atomicAdd(&ddst[ei_dst[e]], 1);
        }
    } else if (b < CB_BASE) {
        const int idx = (b - WP_BASE) * 256 + tid;      // < 81920, exact
        const int l = idx >> 14, rem = idx & 16383;
        const int k = rem >> 7, n = rem & 127;
        unsigned short hi, lo;
        bf16split(W[idx], hi, lo);
        const int off = (l << 14) + ((((k >> 5) * 8 + (n >> 4)) * 64
                        + ((k >> 3) & 3) * 16 + (n & 15)) << 3) + (k & 7);
        whi[off] = hi;
        wlo[off] = lo;
    } else if (b < BN_BASE) {
        const int idx = (b - CB_BASE) * 256 + tid;      // < 327680, exact
        const int l = idx >> 16;
        const int c = (idx >> 7) & 511;
        const int ch = idx & 127;
        const int a0 = c & 7, a1 = (c >> 3) & 7, a2 = c >> 6;
        combo[(size_t)(l * 512 + c) * EMB + ch] = f2bf_rne(
            bemb[(size_t)((l * 3 + 0) * 8 + a0) * EMB + ch] +
            bemb[(size_t)((l * 3 + 1) * 8 + a1) * EMB + ch] +
            bemb[(size_t)((l * 3 + 2) * 8 + a2) * EMB + ch]);
    } else if (b < GB_BASE) {
        const int i = (b - BN_BASE) * 256 + tid;
        if (i < LAYERS * EMB) {
            float s = gamma[i] / sqrtf(var[i] + BN_EPS);
            S[i] = s;
            T[i] = beta[i] - mean[i] * s;
        }
    } else if (b < AB_BASE) {
        const int g = (b - GB_BASE) * 256 + tid;
        if (g > N_GRAPHS) return;
        if (g == N_GRAPHS) { gptr[g] = N_NODES; return; }
        int lo = 0, hi = N_NODES;
        while (lo < hi) {
            int mid = (lo + hi) >> 1;
            if (batch[mid] < g) lo = mid + 1; else hi = mid;
        }
        gptr[g] = lo;
    } else {
        const int idx = (b - AB_BASE) * 256 + tid;      // < 73728, exact
        aembb[idx] = f2bf_rne(aemb[idx]);
    }
}

// ---------------------------------------------------------------------------
// scan1: per-chunk sums of ddst
// ---------------------------------------------------------------------------
__global__ __launch_bounds__(256) void scan1(const int* __restrict__ deg, int* __restrict__ partial) {
    __shared__ int sd[256];
    const int base = blockIdx.x * SCAN_CHUNK + threadIdx.x * 8;
    int s = 0;
#pragma unroll
    for (int i = 0; i < 8; ++i) { int idx = base + i; s += (idx < N_NODES) ? deg[idx] : 0; }
    sd[threadIdx.x] = s; __syncthreads();
    for (int off = 128; off > 0; off >>= 1) {
        if (threadIdx.x < off) sd[threadIdx.x] += sd[threadIdx.x + off];
        __syncthreads();
    }
    if (threadIdx.x == 0) partial[blockIdx.x] = sd[0];
}

// ---------------------------------------------------------------------------
// scan3: block computes its own offset from partials, then scans its chunk.
// ---------------------------------------------------------------------------
__global__ __launch_bounds__(256) void scan3(const int* __restrict__ deg,
                                             const int* __restrict__ partial,
                                             int* __restrict__ rowptr) {
    __shared__ int sd[256];
    __shared__ int base_off;
    const int tid = threadIdx.x;
    if (tid == 0) {
        int acc = 0;
        for (int i = 0; i < (int)blockIdx.x; ++i) acc += partial[i];
        base_off = acc;
    }
    const int base = blockIdx.x * SCAN_CHUNK + tid * 8;
    int loc[8]; int s = 0;
#pragma unroll
    for (int i = 0; i < 8; ++i) { int idx = base + i; loc[i] = (idx < N_NODES) ? deg[idx] : 0; s += loc[i]; }
    sd[tid] = s; __syncthreads();
    for (int off = 1; off < 256; off <<= 1) {
        int v = (tid >= off) ? sd[tid - off] : 0;
        __syncthreads();
        sd[tid] += v;
        __syncthreads();
    }
    int excl = base_off + sd[tid] - s;
#pragma unroll
    for (int i = 0; i < 8; ++i) {
        int idx = base + i;
        if (idx < N_NODES) { rowptr[idx] = excl; excl += loc[i]; }
    }
    if (blockIdx.x == 0 && tid == 0) rowptr[N_NODES] = N_EDGES;
}

// ---------------------------------------------------------------------------
// Scatter edges into dst-CSR. epk = src | combo<<18 ; enrm = norm.
// ---------------------------------------------------------------------------
__global__ void scatter_k(const int* __restrict__ srcs, const int* __restrict__ dsts,
                          const int* __restrict__ eattr, const int* __restrict__ dsrc,
                          const int* __restrict__ rowptr, int* __restrict__ fill,
                          int* __restrict__ epk, float* __restrict__ enrm) {
    int e = blockIdx.x * blockDim.x + threadIdx.x;
    if (e >= N_EDGES) return;
    const int s = srcs[e];
    const int d = dsts[e];
    const int pos = rowptr[d] + atomicAdd(&fill[d], 1);
    const int c = eattr[e * 3] | (eattr[e * 3 + 1] << 3) | (eattr[e * 3 + 2] << 6);
    epk[pos] = s | (c << 18);
    enrm[pos] = rsqrtf((float)(dsrc[s] + 1) * (float)(dsrc[d] + 1));
}

// ---------------------------------------------------------------------------
// MFMA phase for 1024-thread / 64-row blocks (enc_gemm).
// ---------------------------------------------------------------------------
__device__ __forceinline__ void mfma_tile64(
    unsigned short (*AhAl)[64][136],
    const short8* __restrict__ Bh, const short8* __restrict__ Bl,
    const float* __restrict__ bias, unsigned short* __restrict__ XLout,
    size_t rows, int tid) {
    const int wave = tid >> 6;          // 0..15
    const int lane = tid & 63;
    const int quad = lane >> 4;
    const int n15  = lane & 15;
    const int rt   = wave & 3;          // row-tile 0..3
    const int cp   = wave >> 2;         // col-pair 0..3
    const int arow = rt * 16 + n15;

    float4v acc0 = (float4v)(0.f);
    float4v acc1 = (float4v)(0.f);
#pragma unroll
    for (int ks = 0; ks < 4; ++ks) {
        const int k0 = ks * 32 + quad * 8;
        const short8 ah = *(const short8*)&AhAl[0][arow][k0];
        const short8 al = *(const short8*)&AhAl[1][arow][k0];
        const short8 bh0 = Bh[(ks * 8 + cp * 2 + 0) * 64 + lane];
        const short8 bl0 = Bl[(ks * 8 + cp * 2 + 0) * 64 + lane];
        const short8 bh1 = Bh[(ks * 8 + cp * 2 + 1) * 64 + lane];
        const short8 bl1 = Bl[(ks * 8 + cp * 2 + 1) * 64 + lane];
        acc0 = __builtin_amdgcn_mfma_f32_16x16x32_bf16(ah, bh0, acc0, 0, 0, 0);
        acc0 = __builtin_amdgcn_mfma_f32_16x16x32_bf16(ah, bl0, acc0, 0, 0, 0);
        acc0 = __builtin_amdgcn_mfma_f32_16x16x32_bf16(al, bh0, acc0, 0, 0, 0);
        acc1 = __builtin_amdgcn_mfma_f32_16x16x32_bf16(ah, bh1, acc1, 0, 0, 0);
        acc1 = __builtin_amdgcn_mfma_f32_16x16x32_bf16(ah, bl1, acc1, 0, 0, 0);
        acc1 = __builtin_amdgcn_mfma_f32_16x16x32_bf16(al, bh1, acc1, 0, 0, 0);
    }

    const size_t rowBase = rows + rt * 16 + quad * 4;
    const int col0 = (cp * 2 + 0) * 16 + n15;
    const int col1 = (cp * 2 + 1) * 16 + n15;
    const float bc0 = bias[col0];
    const float bc1 = bias[col1];
#pragma unroll
    for (int r = 0; r < 4; ++r) {
        XLout[(rowBase + r) * EMB + col0] = f2bf_rne(acc0[r] + bc0);
        XLout[(rowBase + r) * EMB + col1] = f2bf_rne(acc1[r] + bc1);
    }
}

// ---------------------------------------------------------------------------
// MFMA phase for 256-thread / 16-row blocks (gather_gemm).
// ---------------------------------------------------------------------------
__device__ __forceinline__ void mfma_tile16(
    unsigned short (*AhAl)[16][136],
    const short8* __restrict__ Bh, const short8* __restrict__ Bl,
    const float* __restrict__ bias, unsigned short* __restrict__ XLout,
    size_t rows, int tid) {
    const int wave = tid >> 6;          // 0..3
    const int lane = tid & 63;
    const int quad = lane >> 4;
    const int n15  = lane & 15;
    const int cp   = wave;              // col-pair 0..3
    const int arow = n15;

    float4v acc0 = (float4v)(0.f);
    float4v acc1 = (float4v)(0.f);
#pragma unroll
    for (int ks = 0; ks < 4; ++ks) {
        const int k0 = ks * 32 + quad * 8;
        const short8 ah = *(const short8*)&AhAl[0][arow][k0];
        const short8 al = *(const short8*)&AhAl[1][arow][k0];
        const short8 bh0 = Bh[(ks * 8 + cp * 2 + 0) * 64 + lane];
        const short8 bl0 = Bl[(ks * 8 + cp * 2 + 0) * 64 + lane];
        const short8 bh1 = Bh[(ks * 8 + cp * 2 + 1) * 64 + lane];
        const short8 bl1 = Bl[(ks * 8 + cp * 2 + 1) * 64 + lane];
        acc0 = __builtin_amdgcn_mfma_f32_16x16x32_bf16(ah, bh0, acc0, 0, 0, 0);
        acc0 = __builtin_amdgcn_mfma_f32_16x16x32_bf16(ah, bl0, acc0, 0, 0, 0);
        acc0 = __builtin_amdgcn_mfma_f32_16x16x32_bf16(al, bh0, acc0, 0, 0, 0);
        acc1 = __builtin_amdgcn_mfma_f32_16x16x32_bf16(ah, bh1, acc1, 0, 0, 0);
        acc1 = __builtin_amdgcn_mfma_f32_16x16x32_bf16(ah, bl1, acc1, 0, 0, 0);
        acc1 = __builtin_amdgcn_mfma_f32_16x16x32_bf16(al, bh1, acc1, 0, 0, 0);
    }

    const size_t rowBase = rows + quad * 4;
    const int col0 = (cp * 2 + 0) * 16 + n15;
    const int col1 = (cp * 2 + 1) * 16 + n15;
    const float bc0 = bias[col0];
    const float bc1 = bias[col1];
#pragma unroll
    for (int r = 0; r < 4; ++r) {
        XLout[(rowBase + r) * EMB + col0] = f2bf_rne(acc0[r] + bc0);
        XLout[(rowBase + r) * EMB + col1] = f2bf_rne(acc1[r] + bc1);
    }
}

// ---------------------------------------------------------------------------
// Fused atom-encoder + GEMM layer 0 (1024 threads, 64 rows). aemb table in
// bf16: ONE 16B load per feature per lane.
// ---------------------------------------------------------------------------
__global__ __launch_bounds__(1024, 8) void enc_gemm(
    const int* __restrict__ x, const unsigned short* __restrict__ aembb,
    const unsigned short* __restrict__ whi, const unsigned short* __restrict__ wlo,
    const float* __restrict__ bias, unsigned short* __restrict__ XL) {
    __shared__ unsigned short AhAl[2][64][136];
    const int tid = threadIdx.x;
    const int q = tid & 15, qw = tid >> 4;     // 64 quarter-waves
    const int c0 = q * 8;
    const size_t rows = (size_t)blockIdx.x * 64;

    {
        const size_t n = rows + qw;
        float4 a0 = make_float4(0.f, 0.f, 0.f, 0.f), a1 = a0;
#pragma unroll
        for (int ff = 0; ff < 9; ++ff) {
            const int v = x[n * 9 + ff];
            const ushort8v e = *(const ushort8v*)&aembb[(size_t)(ff * 64 + v) * EMB + c0];
            a0.x += bf2f(e[0]); a0.y += bf2f(e[1]);
            a0.z += bf2f(e[2]); a0.w += bf2f(e[3]);
            a1.x += bf2f(e[4]); a1.y += bf2f(e[5]);
            a1.z += bf2f(e[6]); a1.w += bf2f(e[7]);
        }
        ushort4 hi, lo;
        bf16split(a0.x, hi.x, lo.x); bf16split(a0.y, hi.y, lo.y);
        bf16split(a0.z, hi.z, lo.z); bf16split(a0.w, hi.w, lo.w);
        *(ushort4*)&AhAl[0][qw][c0] = hi;
        *(ushort4*)&AhAl[1][qw][c0] = lo;
        bf16split(a1.x, hi.x, lo.x); bf16split(a1.y, hi.y, lo.y);
        bf16split(a1.z, hi.z, lo.z); bf16split(a1.w, hi.w, lo.w);
        *(ushort4*)&AhAl[0][qw][c0 + 4] = hi;
        *(ushort4*)&AhAl[1][qw][c0 + 4] = lo;
    }
    __syncthreads();
    mfma_tile64(AhAl, (const short8*)whi, (const short8*)wlo, bias, XL, rows, tid);
}

// ---------------------------------------------------------------------------
// Fused gather(layer l) + BN_l + ReLU + GEMM(layer l+1) (256 threads,
// 16 rows): 16 quarter-waves x 1 node; small barrier groups (8/CU).
// ---------------------------------------------------------------------------
__global__ __launch_bounds__(256, 8) void gather_gemm(
    const int* __restrict__ rowptr, const int* __restrict__ epk,
    const float* __restrict__ enrm, const unsigned short* __restrict__ combo,
    const float* __restrict__ root, const int* __restrict__ dsrc,
    const float* __restrict__ bnS, const float* __restrict__ bnT,
    const unsigned short* __restrict__ whi, const unsigned short* __restrict__ wlo,
    const float* __restrict__ bias,
    const unsigned short* __restrict__ XLin, unsigned short* __restrict__ XLout) {
    __shared__ unsigned short AhAl[2][16][136];
    const int tid = threadIdx.x;
    const int q = tid & 15, qw = tid >> 4;
    const int c0 = q * 8;
    const size_t rows = (size_t)blockIdx.x * 16;

    {
        const size_t n = rows + qw;
        const float4 r40 = *(const float4*)&root[c0];
        const float4 r41 = *(const float4*)&root[c0 + 4];
        const float4 s40 = *(const float4*)&bnS[c0];
        const float4 s41 = *(const float4*)&bnS[c0 + 4];
        const float4 t40 = *(const float4*)&bnT[c0];
        const float4 t41 = *(const float4*)&bnT[c0 + 4];
        const float dinv = 1.0f / (float)(dsrc[n] + 1);
        const ushort8v xn = *(const ushort8v*)&XLin[n * EMB + c0];
        float4 a0, a1;
        a0.x = fmaxf(bf2f(xn[0]) + r40.x, 0.f) * dinv;
        a0.y = fmaxf(bf2f(xn[1]) + r40.y, 0.f) * dinv;
        a0.z = fmaxf(bf2f(xn[2]) + r40.z, 0.f) * dinv;
        a0.w = fmaxf(bf2f(xn[3]) + r40.w, 0.f) * dinv;
        a1.x = fmaxf(bf2f(xn[4]) + r41.x, 0.f) * dinv;
        a1.y = fmaxf(bf2f(xn[5]) + r41.y, 0.f) * dinv;
        a1.z = fmaxf(bf2f(xn[6]) + r41.z, 0.f) * dinv;
        a1.w = fmaxf(bf2f(xn[7]) + r41.w, 0.f) * dinv;

        const int beg = rowptr[n], end = rowptr[n + 1];
        int pk = 0; float wgt = 0.f;
        if (beg < end) { pk = epk[beg]; wgt = enrm[beg]; }
        for (int e = beg; e < end; ++e) {
            const int pk_c = pk; const float w_c = wgt;
            if (e + 1 < end) { pk = epk[e + 1]; wgt = enrm[e + 1]; }   // prefetch
            const size_t sb = (size_t)(pk_c & 0x3FFFF) * EMB + c0;
            const size_t cbx = (size_t)(pk_c >> 18) * EMB + c0;
            const ushort8v xv = *(const ushort8v*)&XLin[sb];
            const ushort8v cb = *(const ushort8v*)&combo[cbx];
            a0.x += fmaxf(bf2f(xv[0]) + bf2f(cb[0]), 0.f) * w_c;
            a0.y += fmaxf(bf2f(xv[1]) + bf2f(cb[1]), 0.f) * w_c;
            a0.z += fmaxf(bf2f(xv[2]) + bf2f(cb[2]), 0.f) * w_c;
            a0.w += fmaxf(bf2f(xv[3]) + bf2f(cb[3]), 0.f) * w_c;
            a1.x += fmaxf(bf2f(xv[4]) + bf2f(cb[4]), 0.f) * w_c;
            a1.y += fmaxf(bf2f(xv[5]) + bf2f(cb[5]), 0.f) * w_c;
            a1.z += fmaxf(bf2f(xv[6]) + bf2f(cb[6]), 0.f) * w_c;
            a1.w += fmaxf(bf2f(xv[7]) + bf2f(cb[7]), 0.f) * w_c;
        }
        float4 h0, h1;
        h0.x = fmaxf(fmaf(a0.x, s40.x, t40.x), 0.f);
        h0.y = fmaxf(fmaf(a0.y, s40.y, t40.y), 0.f);
        h0.z = fmaxf(fmaf(a0.z, s40.z, t40.z), 0.f);
        h0.w = fmaxf(fmaf(a0.w, s40.w, t40.w), 0.f);
        h1.x = fmaxf(fmaf(a1.x, s41.x, t41.x), 0.f);
        h1.y = fmaxf(fmaf(a1.y, s41.y, t41.y), 0.f);
        h1.z = fmaxf(fmaf(a1.z, s41.z, t41.z), 0.f);
        h1.w = fmaxf(fmaf(a1.w, s41.w, t41.w), 0.f);
        ushort4 hi, lo;
        bf16split(h0.x, hi.x, lo.x); bf16split(h0.y, hi.y, lo.y);
        bf16split(h0.z, hi.z, lo.z); bf16split(h0.w, hi.w, lo.w);
        *(ushort4*)&AhAl[0][qw][c0] = hi;
        *(ushort4*)&AhAl[1][qw][c0] = lo;
        bf16split(h1.x, hi.x, lo.x); bf16split(h1.y, hi.y, lo.y);
        bf16split(h1.z, hi.z, lo.z); bf16split(h1.w, hi.w, lo.w);
        *(ushort4*)&AhAl[0][qw][c0 + 4] = hi;
        *(ushort4*)&AhAl[1][qw][c0 + 4] = lo;
    }
    __syncthreads();
    mfma_tile16(AhAl, (const short8*)whi, (const short8*)wlo, bias, XLout, rows, tid);
}

// ---------------------------------------------------------------------------
// Fused final gather(layer 4) + BN4 + pool + head. Flat edge-range pooling
// (BN affine + pool linear), one 512-thread block per graph, no atomics.
// ---------------------------------------------------------------------------
__global__ __launch_bounds__(512) void gather_pool_head(
    const int* __restrict__ rowptr, const int* __restrict__ epk,
    const float* __restrict__ enrm, const unsigned short* __restrict__ combo,
    const float* __restrict__ root, const int* __restrict__ dsrc,
    const float* __restrict__ S4, const float* __restrict__ T4,
    const int* __restrict__ gptr, const unsigned short* __restrict__ XLin,
    const float* __restrict__ HW, const float* __restrict__ hb,
    float* __restrict__ OUT) {
    __shared__ float red[32][EMB];
    __shared__ float hr[EMB];
    const int gph = blockIdx.x;
    const int q = threadIdx.x & 15, qw = threadIdx.x >> 4;   // 32 quarter-waves
    const int c0 = q * 8;
    const int nbeg = gptr[gph], nend = gptr[gph + 1];
    const int ebeg = rowptr[nbeg], eend = rowptr[nend];

    const float4 r40 = *(const float4*)&root[c0];
    const float4 r41 = *(const float4*)&root[c0 + 4];

    float4 seg0 = make_float4(0.f, 0.f, 0.f, 0.f), seg1 = seg0;
    // self terms over the graph's node range
    for (int n = nbeg + qw; n < nend; n += 32) {
        const float dinv = 1.0f / (float)(dsrc[n] + 1);
        const ushort8v xn = *(const ushort8v*)&XLin[(size_t)n * EMB + c0];
        seg0.x += fmaxf(bf2f(xn[0]) + r40.x, 0.f) * dinv;
        seg0.y += fmaxf(bf2f(xn[1]) + r40.y, 0.f) * dinv;
        seg0.z += fmaxf(bf2f(xn[2]) + r40.z, 0.f) * dinv;
        seg0.w += fmaxf(bf2f(xn[3]) + r40.w, 0.f) * dinv;
        seg1.x += fmaxf(bf2f(xn[4]) + r41.x, 0.f) * dinv;
        seg1.y += fmaxf(bf2f(xn[5]) + r41.y, 0.f) * dinv;
        seg1.z += fmaxf(bf2f(xn[6]) + r41.z, 0.f) * dinv;
        seg1.w += fmaxf(bf2f(xn[7]) + r41.w, 0.f) * dinv;
    }
    // messages over the graph's contiguous edge range (dst identity unused)
    for (int i = ebeg + qw; i < eend; i += 32) {
        const int pk = epk[i];
        const float w = enrm[i];
        const size_t sb = (size_t)(pk & 0x3FFFF) * EMB + c0;
        const size_t cbx = (size_t)(pk >> 18) * EMB + c0;
        const ushort8v xv = *(const ushort8v*)&XLin[sb];
        const ushort8v cb = *(const ushort8v*)&combo[cbx];
        seg0.x += fmaxf(bf2f(xv[0]) + bf2f(cb[0]), 0.f) * w;
        seg0.y += fmaxf(bf2f(xv[1]) + bf2f(cb[1]), 0.f) * w;
        seg0.z += fmaxf(bf2f(xv[2]) + bf2f(cb[2]), 0.f) * w;
        seg0.w += fmaxf(bf2f(xv[3]) + bf2f(cb[3]), 0.f) * w;
        seg1.x += fmaxf(bf2f(xv[4]) + bf2f(cb[4]), 0.f) * w;
        seg1.y += fmaxf(bf2f(xv[5]) + bf2f(cb[5]), 0.f) * w;
        seg1.z += fmaxf(bf2f(xv[6]) + bf2f(cb[6]), 0.f) * w;
        seg1.w += fmaxf(bf2f(xv[7]) + bf2f(cb[7]), 0.f) * w;
    }
    *(float4*)&red[qw][c0] = seg0;
    *(float4*)&red[qw][c0 + 4] = seg1;
    __syncthreads();

    const int t = threadIdx.x;
    if (t < EMB) {
        float v = 0.f;
#pragma unroll
        for (int r = 0; r < 32; ++r) v += red[r][t];
        hr[t] = fmaf(v, S4[t], T4[t] * (float)(nend - nbeg));
    }
    __syncthreads();
    if (t < EMB) {
        float o = hb[t];
#pragma unroll 8
        for (int k = 0; k < EMB; ++k) o = fmaf(hr[k], HW[(size_t)k * EMB + t], o);
        OUT[(size_t)gph * EMB + t] = o;
    }
}

extern "C" void kernel_launch(void* const* d_in, const int* in_sizes, int n_in,
                              void* d_out, int out_size, void* d_ws, size_t ws_size,
                              hipStream_t stream) {
    const int*   x     = (const int*)d_in[0];
    const int*   ei    = (const int*)d_in[1];    // [2, E]: src then dst
    const int*   ea    = (const int*)d_in[2];    // [E, 3]
    const int*   batch = (const int*)d_in[3];
    const float* aemb  = (const float*)d_in[4];
    const float* bemb  = (const float*)d_in[5];
    const float* W     = (const float*)d_in[6];
    const float* b     = (const float*)d_in[7];
    const float* root  = (const float*)d_in[8];
    const float* bnm   = (const float*)d_in[9];
    const float* bnv   = (const float*)d_in[10];
    const float* bng   = (const float*)d_in[11];
    const float* bnb   = (const float*)d_in[12];
    const float* hW    = (const float*)d_in[13];
    const float* hb    = (const float*)d_in[14];
    float* out = (float*)d_out;

    const size_t NF = (size_t)N_NODES * EMB;
    // bufA/bufB bf16 (NF/2 float slots each); combo bf16; aembb bf16
    const size_t n_float = NF + (size_t)LAYERS * 512 * EMB / 2
                         + 2 * LAYERS * EMB + N_EDGES
                         + 2 * ((size_t)LAYERS * 16384 / 2 + 64)
                         + (9 * 64 * EMB / 2 + 64);
    const size_t n_int   = 3 * (size_t)N_NODES + (N_NODES + 4) + 128
                         + (N_GRAPHS + 4) + N_EDGES;
    const size_t need = (n_float + n_int) * sizeof(float);
    if (ws_size < need) return;  // defensive: fail cleanly, don't fault

    float* f     = (float*)d_ws;
    unsigned short* bufA = (unsigned short*)f; f += NF / 2;
    unsigned short* bufB = (unsigned short*)f; f += NF / 2;
    unsigned short* combo = (unsigned short*)f; f += (size_t)LAYERS * 512 * EMB / 2;
    float* S     = f;                          f += LAYERS * EMB;
    float* T     = f;                          f += LAYERS * EMB;
    float* enrm  = f;                          f += N_EDGES;
    unsigned short* whi = (unsigned short*)f;  f += (size_t)LAYERS * 16384 / 2 + 64;
    unsigned short* wlo = (unsigned short*)f;  f += (size_t)LAYERS * 16384 / 2 + 64;
    unsigned short* aembb = (unsigned short*)f; f += 9 * 64 * EMB / 2 + 64;
    int*   ip    = (int*)f;
    int*   dsrc    = ip;                       ip += N_NODES;
    int*   ddst    = ip;                       ip += N_NODES;
    int*   fill    = ip;                       ip += N_NODES;
    int*   rowptr  = ip;                       ip += N_NODES + 4;
    int*   partial = ip;                       ip += 128;
    int*   gptr    = ip;                       ip += N_GRAPHS + 4;
    int*   epk     = ip;                       ip += N_EDGES;

    hipMemsetAsync(dsrc, 0, 3 * (size_t)N_NODES * sizeof(int), stream);

    prep_all<<<PREP_BLOCKS, 256, 0, stream>>>(
        ei, ei + N_EDGES, dsrc, ddst, W, whi, wlo, bemb, combo,
        bnm, bnv, bng, bnb, S, T, batch, gptr, aemb, aembb);
    scan1<<<N_CHUNKS, 256, 0, stream>>>(ddst, partial);
    scan3<<<N_CHUNKS, 256, 0, stream>>>(ddst, partial, rowptr);
    scatter_k<<<(N_EDGES + 255) / 256, 256, 0, stream>>>(ei, ei + N_EDGES, ea, dsrc,
                                                         rowptr, fill, epk, enrm);

    // L0: encoder fused with GEMM-0 -> XL0 (bf16) in bufA (64-row blocks)
    enc_gemm<<<N_NODES / 64, 1024, 0, stream>>>(x, aembb, whi, wlo, b, bufA);

    // L0..L3 gathers fused with next layer's GEMM (16-row blocks); h on-chip.
    unsigned short* in    = bufA;
    unsigned short* other = bufB;
    for (int l = 0; l < 4; ++l) {
        gather_gemm<<<N_NODES / 16, 256, 0, stream>>>(
            rowptr, epk, enrm, combo + (size_t)l * 512 * EMB, root + l * EMB, dsrc,
            S + l * EMB, T + l * EMB,
            whi + (size_t)(l + 1) * 16384, wlo + (size_t)(l + 1) * 16384,
            b + (l + 1) * EMB, /*XLin=*/in, /*XLout=*/other);
        unsigned short* t0 = in; in = other; other = t0;
    }

    // L4 gather fused with BN4 + pool + head, one block per graph, no atomics
    gather_pool_head<<<N_GRAPHS, 512, 0, stream>>>(
        rowptr, epk, enrm, combo + (size_t)4 * 512 * EMB, root + 4 * EMB, dsrc,
        S + 4 * EMB, T + 4 * EMB, gptr, /*XLin=*/in, hW, hb, out);
}